// Round 6
// baseline (60.674 us; speedup 1.0000x reference)
//
#include <hip/hip_runtime.h>
#include <hip/hip_bf16.h>

#define NN 50000      // nodes
#define EE 800000     // edges
#define KD 512        // IN_DIM
#define ND 256        // H*D

typedef __bf16 bf16x8 __attribute__((ext_vector_type(8)));
typedef float f32x4 __attribute__((ext_vector_type(4)));

// fire-and-forget 16B global->LDS copy (dest = wave-uniform base + lane*16)
#define GLD16(g, l) __builtin_amdgcn_global_load_lds( \
    (const __attribute__((address_space(1))) unsigned int*)(g), \
    (__attribute__((address_space(3))) unsigned int*)(l), 16, 0, 0)

// ---------- Kernel 1: fused  (a) W (512x256 f32) -> Wt (256x512 bf16 [n][k])
//                             (b) zero the flags array ----------
__global__ __launch_bounds__(256) void prep_kernel(const float* __restrict__ W,
                                                   __hip_bfloat16* __restrict__ Wt,
                                                   unsigned char* __restrict__ flags) {
    if (blockIdx.x >= 32) {
        int idx = (blockIdx.x - 32) * 256 + threadIdx.x;
        if (idx < 3125) reinterpret_cast<uint4*>(flags)[idx] = (uint4){0, 0, 0, 0};
        return;
    }
    __shared__ __align__(16) __hip_bfloat16 tile[64][72];
    const int bk = blockIdx.x & 7;
    const int bn = blockIdx.x >> 3;
    const int k0 = bk * 64, n0 = bn * 64;
    const int t = threadIdx.x;
    const int r = t >> 2;
    const int c = (t & 3) * 16;
    const float4* src = reinterpret_cast<const float4*>(W + (size_t)(k0 + r) * ND + n0 + c);
#pragma unroll
    for (int i = 0; i < 4; ++i) {
        float4 f = src[i];
        tile[c + i * 4 + 0][r] = __float2bfloat16(f.x);
        tile[c + i * 4 + 1][r] = __float2bfloat16(f.y);
        tile[c + i * 4 + 2][r] = __float2bfloat16(f.z);
        tile[c + i * 4 + 3][r] = __float2bfloat16(f.w);
    }
    __syncthreads();
    uint4* dst = reinterpret_cast<uint4*>(Wt + (size_t)(n0 + r) * KD + k0 + c);
    dst[0] = *reinterpret_cast<const uint4*>(&tile[r][c]);
    dst[1] = *reinterpret_cast<const uint4*>(&tile[r][c + 8]);
}

// ---------- Kernel 2: flags[dst[e]] = 1 via test-and-set ----------
__global__ __launch_bounds__(256) void flag_set_kernel(const int* __restrict__ dst_idx,
                                                       unsigned char* __restrict__ flags) {
    int i = (blockIdx.x * 256 + threadIdx.x) * 4;
    if (i >= EE) return;  // EE % 4 == 0
    int4 d = *reinterpret_cast<const int4*>(dst_idx + i);
    if (flags[d.x] == 0) flags[d.x] = 1;
    if (flags[d.y] == 0) flags[d.y] = 1;
    if (flags[d.z] == 0) flags[d.z] = 1;
    if (flags[d.w] == 0) flags[d.w] = 1;
}

__device__ __forceinline__ bf16x8 cvt8(f32x4 lo, f32x4 hi) {
    union { __hip_bfloat16 h[8]; bf16x8 v; } u;
    u.h[0] = __float2bfloat16(lo[0]); u.h[1] = __float2bfloat16(lo[1]);
    u.h[2] = __float2bfloat16(lo[2]); u.h[3] = __float2bfloat16(lo[3]);
    u.h[4] = __float2bfloat16(hi[0]); u.h[5] = __float2bfloat16(hi[1]);
    u.h[6] = __float2bfloat16(hi[2]); u.h[7] = __float2bfloat16(hi[3]);
    return u.v;
}

// ---------- Kernel 3: out[m][n] = flags[m] ? (x @ W)[m][n] : 0 ----------
// R6: BM=128, BN=256 (x read ONCE), BK=32. 512 threads = 8 waves (2M x 4N),
// wave tile 64x64, acc[4][4].
// Change vs R5: B (Wt, 256 KB, permanently L2-resident) no longer transits
// LDS -- fragments load global->reg WITHIN the same step (no cross-iteration
// register liveness -> no R2-style regalloc collapse). A keeps the proven
// GLD16 + counted-vmcnt + double-barrier skeleton.
// vmcnt bookkeeping (retire = issue order): per iter issue B(kt) [4 loads]
// THEN STAGE_A(kt+1) [2 GLD16]. Manual wait vmcnt(6) => A(kt) landed, with
// B(kt)+A(kt+1) still outstanding. B issued BEFORE A(kt+1) so the compiler's
// auto-wait before the MFMA B-use is vmcnt(2) -- A(kt+1) stays in flight.
// (B issued after A(kt+1) would force vmcnt(0) and kill the pipeline.)
// Barrier-synced staging halves (48->32 KB/step); B's 100 MB moves to the
// fast decoupled L2 path (measured marginal rate ~12.5 TB/s).
// A LDS layout (linear dest; swizzle on per-lane GLOBAL source + ds_read):
//   A buf 16 KB: row m (0..127) x 128 B (32 f32 of k); phys = log ^ ((m&7)<<4)
__global__ __launch_bounds__(512, 4) void gemm_mask_kernel(const float* __restrict__ x,
                                                           const __hip_bfloat16* __restrict__ Wt,
                                                           const unsigned char* __restrict__ flags,
                                                           float* __restrict__ out) {
    __shared__ __align__(16) char As[2][16384];

    const int t = threadIdx.x;
    const int w = t >> 6;             // wave 0..7
    const int l = t & 63;
    const int wm = w >> 2;            // 0..1  (M half)
    const int wn = w & 3;             // 0..3  (N quarter)
    const int m_base = blockIdx.x * 128;

    // ---- A staging sources (per-lane, inverse-swizzled; verified R5) ----
    // dest byte o = i*8192 + w*1024 + l*16 ; row ar = o>>7 (0..127);
    // granule p=(o>>4)&7 ; logical g = p ^ (ar&7); src = x[m_base+ar]+g*16 (+kt*128)
    const char* aSrc[2];
#pragma unroll
    for (int i = 0; i < 2; ++i) {
        int o = i * 8192 + w * 1024 + l * 16;
        int ar = o >> 7;
        int g = ((o >> 4) & 7) ^ (ar & 7);
        int m = m_base + ar; if (m > NN - 1) m = NN - 1;   // clamp (stores guarded)
        aSrc[i] = (const char*)x + (size_t)m * (KD * 4) + g * 16;
    }

    // ---- consume-side ds_read offsets for A (swizzled) ----
    const int fr = l & 15;            // fragment row within 16
    const int fo = l >> 4;            // k sub-block 0..3
    // A: row = wm*64 + tm*16 + fr ; row&7 == l&7
    const int aOff0 = (wm * 64 + fr) * 128 + ((fo * 32) ^ ((l & 7) << 4));

    // ---- B fragment pointers: straight from Wt (L2-resident) ----
    // B[n = wn*64 + tn*16 + fr][k = kt*32 + fo*8], bf16x8 per lane.
    // Per tn-load the 4 quarter-waves cover rows 0..15 x full 64 B contiguous
    // -> 100% cacheline utilization. Step offset kt*64 B folds into the imm.
    const char* bPtr[4];
#pragma unroll
    for (int tn = 0; tn < 4; ++tn)
        bPtr[tn] = (const char*)Wt + (size_t)(wn * 64 + tn * 16 + fr) * (KD * 2) + fo * 16;

    f32x4 acc[4][4];
#pragma unroll
    for (int i = 0; i < 4; ++i)
#pragma unroll
        for (int j = 0; j < 4; ++j) acc[i][j] = (f32x4){0.f, 0.f, 0.f, 0.f};

#define STAGE_A(kt, buf)                                          \
    {                                                             \
        GLD16(aSrc[0] + (kt) * 128, &As[buf][w * 1024]);          \
        GLD16(aSrc[1] + (kt) * 128, &As[buf][8192 + w * 1024]);   \
    }

    // prologue: step 0's A in flight (2 loads/wave)
    STAGE_A(0, 0);

#pragma unroll
    for (int kt = 0; kt < 16; ++kt) {
        const int cur = kt & 1;

        // ---- issue B(kt) FIRST (older than A(kt+1) in the vmcnt queue) ----
        bf16x8 bfr[4];
#pragma unroll
        for (int tn = 0; tn < 4; ++tn)
            bfr[tn] = *reinterpret_cast<const bf16x8*>(bPtr[tn] + kt * 64);

        if (kt < 15) {
            STAGE_A(kt + 1, cur ^ 1);  // target buf last read at kt-1 (end-barrier-protected)
            asm volatile("s_waitcnt vmcnt(6)" ::: "memory");   // A(kt) landed; B(kt)+A(kt+1) in flight
        } else {
            asm volatile("s_waitcnt vmcnt(4)" ::: "memory");   // A(15) landed; B(15) in flight
        }
        __builtin_amdgcn_s_barrier();      // all waves' A(kt) in LDS
        __builtin_amdgcn_sched_barrier(0); // keep ds_reads below the barrier

        // tm-halves keep live A fragments at 2 (acc = 64 VGPR)
#pragma unroll
        for (int h = 0; h < 2; ++h) {
            bf16x8 afr[2];
#pragma unroll
            for (int u = 0; u < 2; ++u) {
                const int p = aOff0 + (h * 2 + u) * 2048;
                f32x4 lo = *reinterpret_cast<const f32x4*>(&As[cur][p]);
                f32x4 hi = *reinterpret_cast<const f32x4*>(&As[cur][p ^ 16]);
                afr[u] = cvt8(lo, hi);
            }
#pragma unroll
            for (int u = 0; u < 2; ++u)
#pragma unroll
                for (int tn = 0; tn < 4; ++tn)
                    acc[h * 2 + u][tn] = __builtin_amdgcn_mfma_f32_16x16x32_bf16(afr[u], bfr[tn], acc[h * 2 + u][tn], 0, 0, 0);
        }

        __builtin_amdgcn_s_barrier();      // all waves done reading As[cur]
    }
#undef STAGE_A

    // ---- epilogue: C/D layout col=lane&15, row=(lane>>4)*4+r ----
    const int col = l & 15;
    const int rq = (l >> 4) * 4;
#pragma unroll
    for (int tm = 0; tm < 4; ++tm) {
#pragma unroll
        for (int r = 0; r < 4; ++r) {
            const int m = m_base + wm * 64 + tm * 16 + rq + r;
            if (m < NN) {
                const float fl = (float)flags[m];
                float* orow = out + (size_t)m * ND + wn * 64 + col;
#pragma unroll
                for (int tn = 0; tn < 4; ++tn)
                    orow[tn * 16] = acc[tm][tn][r] * fl;
            }
        }
    }
}

extern "C" void kernel_launch(void* const* d_in, const int* in_sizes, int n_in,
                              void* d_out, int out_size, void* d_ws, size_t ws_size,
                              hipStream_t stream) {
    const float* x = (const float*)d_in[0];          // (N, 512) f32
    const int* edge_index = (const int*)d_in[1];     // (2, E) i32: row0=src, row1=dst
    const float* W = (const float*)d_in[3];          // (512, 256) f32
    float* out = (float*)d_out;                      // (N, 256) f32

    unsigned char* flags = (unsigned char*)d_ws;                       // NN bytes (16B-aligned)
    __hip_bfloat16* Wt = (__hip_bfloat16*)((char*)d_ws + 65536);       // 256 KB

    prep_kernel<<<45, 256, 0, stream>>>(W, Wt, flags);
    flag_set_kernel<<<(EE / 4 + 255) / 256, 256, 0, stream>>>(edge_index + EE, flags);
    gemm_mask_kernel<<<(NN + 127) / 128, 512, 0, stream>>>(x, Wt, flags, out);
}

// Round 7
// 44.759 us; speedup vs baseline: 1.3556x; 1.3556x over previous
//
#include <hip/hip_runtime.h>
#include <hip/hip_bf16.h>

#define NN 50000      // nodes
#define EE 800000     // edges
#define KD 512        // IN_DIM
#define ND 256        // H*D

typedef __bf16 bf16x8 __attribute__((ext_vector_type(8)));
typedef float f32x4 __attribute__((ext_vector_type(4)));

// fire-and-forget 16B global->LDS copy (dest = wave-uniform base + lane*16)
#define GLD16(g, l) __builtin_amdgcn_global_load_lds( \
    (const __attribute__((address_space(1))) unsigned int*)(g), \
    (__attribute__((address_space(3))) unsigned int*)(l), 16, 0, 0)

// ---------- Kernel 1: fused  (a) W (512x256 f32) -> Wt (256x512 bf16 [n][k])
//                             (b) zero the flags array ----------
__global__ __launch_bounds__(256) void prep_kernel(const float* __restrict__ W,
                                                   __hip_bfloat16* __restrict__ Wt,
                                                   unsigned char* __restrict__ flags) {
    if (blockIdx.x >= 32) {
        int idx = (blockIdx.x - 32) * 256 + threadIdx.x;
        if (idx < 3125) reinterpret_cast<uint4*>(flags)[idx] = (uint4){0, 0, 0, 0};
        return;
    }
    __shared__ __align__(16) __hip_bfloat16 tile[64][72];
    const int bk = blockIdx.x & 7;
    const int bn = blockIdx.x >> 3;
    const int k0 = bk * 64, n0 = bn * 64;
    const int t = threadIdx.x;
    const int r = t >> 2;
    const int c = (t & 3) * 16;
    const float4* src = reinterpret_cast<const float4*>(W + (size_t)(k0 + r) * ND + n0 + c);
#pragma unroll
    for (int i = 0; i < 4; ++i) {
        float4 f = src[i];
        tile[c + i * 4 + 0][r] = __float2bfloat16(f.x);
        tile[c + i * 4 + 1][r] = __float2bfloat16(f.y);
        tile[c + i * 4 + 2][r] = __float2bfloat16(f.z);
        tile[c + i * 4 + 3][r] = __float2bfloat16(f.w);
    }
    __syncthreads();
    uint4* dst = reinterpret_cast<uint4*>(Wt + (size_t)(n0 + r) * KD + k0 + c);
    dst[0] = *reinterpret_cast<const uint4*>(&tile[r][c]);
    dst[1] = *reinterpret_cast<const uint4*>(&tile[r][c + 8]);
}

// ---------- Kernel 2: flags[dst[e]] = 1 via test-and-set ----------
__global__ __launch_bounds__(256) void flag_set_kernel(const int* __restrict__ dst_idx,
                                                       unsigned char* __restrict__ flags) {
    int i = (blockIdx.x * 256 + threadIdx.x) * 4;
    if (i >= EE) return;  // EE % 4 == 0
    int4 d = *reinterpret_cast<const int4*>(dst_idx + i);
    if (flags[d.x] == 0) flags[d.x] = 1;
    if (flags[d.y] == 0) flags[d.y] = 1;
    if (flags[d.z] == 0) flags[d.z] = 1;
    if (flags[d.w] == 0) flags[d.w] = 1;
}

__device__ __forceinline__ bf16x8 cvt8(f32x4 lo, f32x4 hi) {
    union { __hip_bfloat16 h[8]; bf16x8 v; } u;
    u.h[0] = __float2bfloat16(lo[0]); u.h[1] = __float2bfloat16(lo[1]);
    u.h[2] = __float2bfloat16(lo[2]); u.h[3] = __float2bfloat16(lo[3]);
    u.h[4] = __float2bfloat16(hi[0]); u.h[5] = __float2bfloat16(hi[1]);
    u.h[6] = __float2bfloat16(hi[2]); u.h[7] = __float2bfloat16(hi[3]);
    return u.v;
}

// ---------- Kernel 3: out[m][n] = flags[m] ? (x @ W)[m][n] : 0 ----------
// R7: BM=128, BN=256 (x read ONCE), BK=32, 512 thr = 8 waves (2Mx4N),
// wave tile 64x64, acc[4][4]. B path verbatim R5 (GLD16 depth-1, swizzled).
// A path redesigned (T14 async-split, bf16-in-LDS):
//   per thread: issue 2x global_load_dwordx4 f32 for step kt+2 EARLY (right
//   after staging issue), cvt+ds_write for kt+1 AFTER compute -- HBM latency
//   lands under the MFMA phase (de-bursts the barrier-locked stream).
//   A in LDS is bf16, padded stride 80 B: write slots (5r+q)%8 and read slots
//   (5*fr+fo)%8 both uniform over 8 chunk-slots -> b128 bank floor, no
//   swizzle needed (ds_write is lane-addressed, padding legal).
//   LDS traffic/step: 88 KB vs R5's 144 KB; consume-side cvt removed.
// ONE barrier per step (staging issued after the barrier; buffer WAR is
// protected by the same barrier: buf (kt+1)&1 was read at kt-1, all waves
// passed barrier(kt) before any write/GLD16 targets it).
// vmcnt ledger (in-order retire; sched_barrier(0) pins issue order):
//   per step issue: [B-GLD16(kt+1) x2][gA(kt+2) x2]
//   item1:  vmcnt(2) lgkmcnt(0)  -> B(kt) landed; gA(kt+1) may fly
//   item5:  vmcnt(4)             -> gA(kt+1) landed; B(kt+1)+gA(kt+2) fly
__global__ __launch_bounds__(512, 4) void gemm_mask_kernel(const float* __restrict__ x,
                                                           const __hip_bfloat16* __restrict__ Wt,
                                                           const unsigned char* __restrict__ flags,
                                                           float* __restrict__ out) {
    __shared__ __align__(16) char As[2][10240];   // 128 rows x 80 B (64 data + 16 pad), bf16
    __shared__ __align__(16) char Bs[2][16384];   // verbatim R5

    const int t = threadIdx.x;
    const int w = t >> 6;             // wave 0..7
    const int l = t & 63;
    const int wm = w >> 2;            // 0..1  (M half)
    const int wn = w & 3;             // 0..3  (N quarter)
    const int m_base = blockIdx.x * 128;

    // ---- A staging: thread -> row ar = t>>2 (0..127), quarter q = t&3 ----
    // global f32 k-range per step: [kt*32 + q*8, +8) -> bytes kt*128 + q*32
    const int ar = t >> 2;
    const int q = t & 3;
    const char* aSrcR;
    {
        int m = m_base + ar; if (m > NN - 1) m = NN - 1;   // clamp (stores guarded)
        aSrcR = (const char*)x + (size_t)m * (KD * 4) + q * 32;
    }
    const int aWr = ar * 80 + q * 16;  // LDS byte dest for this thread's 8 bf16

    // ---- B staging sources (per-lane, inverse-swizzled; verbatim R5) ----
    const char* bSrc[2];
#pragma unroll
    for (int j = 0; j < 2; ++j) {
        int o = j * 8192 + w * 1024 + l * 16;
        int br = o >> 7;
        int g = ((o >> 4) & 7) ^ (br & 7);
        int n = 2 * br + (g >> 2);
        bSrc[j] = (const char*)Wt + (size_t)n * (KD * 2) + (g & 3) * 16;
    }

    // ---- consume-side offsets ----
    const int fr = l & 15;            // fragment row within 16
    const int fo = l >> 4;            // k sub-block 0..3
    // A (bf16, stride 80): row = wm*64 + tm*16 + fr, col byte = fo*16
    const int aOff = (wm * 64 + fr) * 80 + fo * 16;
    // B (verbatim R5)
    const int bOff = (wn * 32 + (fr >> 1)) * 128 +
                     (((fr & 1) * 64 + fo * 16) ^ (((fr >> 1) & 7) << 4));

    f32x4 acc[4][4];
#pragma unroll
    for (int i = 0; i < 4; ++i)
#pragma unroll
        for (int j = 0; j < 4; ++j) acc[i][j] = (f32x4){0.f, 0.f, 0.f, 0.f};

    f32x4 ga[2][2];   // gA reg slots; slot kt&1 holds step kt's f32 data (unrolled -> static idx)

#define LOAD_GA(kt)                                                              \
    {                                                                            \
        ga[(kt) & 1][0] = *reinterpret_cast<const f32x4*>(aSrcR + (kt) * 128);   \
        ga[(kt) & 1][1] = *reinterpret_cast<const f32x4*>(aSrcR + (kt) * 128 + 16); \
    }
#define STAGE_B(kt)                                                  \
    {                                                                \
        GLD16(bSrc[0] + (kt) * 64, &Bs[(kt) & 1][w * 1024]);         \
        GLD16(bSrc[1] + (kt) * 64, &Bs[(kt) & 1][8192 + w * 1024]);  \
    }
#define WRITE_A(kt)                                                  \
    *reinterpret_cast<bf16x8*>(&As[(kt) & 1][aWr]) =                 \
        cvt8(ga[(kt) & 1][0], ga[(kt) & 1][1]);

    // ---- prologue: queue = [gA(0) x2][B(0) x2][gA(1) x2] ----
    LOAD_GA(0);
    __builtin_amdgcn_sched_barrier(0);
    STAGE_B(0);
    __builtin_amdgcn_sched_barrier(0);
    LOAD_GA(1);
    __builtin_amdgcn_sched_barrier(0);
    asm volatile("s_waitcnt vmcnt(4)" ::: "memory");   // gA(0) landed
    WRITE_A(0);

#pragma unroll
    for (int kt = 0; kt < 16; ++kt) {
        const int cur = kt & 1;
        // item1: B(kt) landed (oldest 2); this wave's ds_writes done; barrier
        if (kt < 15) {
            asm volatile("s_waitcnt vmcnt(2) lgkmcnt(0)" ::: "memory");
        } else {
            asm volatile("s_waitcnt vmcnt(0) lgkmcnt(0)" ::: "memory");
        }
        __builtin_amdgcn_s_barrier();      // LDS A(kt), B(kt) globally ready
        __builtin_amdgcn_sched_barrier(0);

        // item2+3: issue next staging (order pinned: B first, then gA)
        if (kt < 15) STAGE_B(kt + 1);
        __builtin_amdgcn_sched_barrier(0);
        if (kt < 14) LOAD_GA(kt + 2);
        __builtin_amdgcn_sched_barrier(0);

        // item4: compute(kt)
        bf16x8 bfr[4];
#pragma unroll
        for (int tn = 0; tn < 4; ++tn)
            bfr[tn] = *reinterpret_cast<const bf16x8*>(&Bs[cur][bOff + tn * 1024]);
#pragma unroll
        for (int h = 0; h < 2; ++h) {
            bf16x8 afr[2];
#pragma unroll
            for (int u = 0; u < 2; ++u)
                afr[u] = *reinterpret_cast<const bf16x8*>(&As[cur][aOff + (h * 2 + u) * 1280]);
#pragma unroll
            for (int u = 0; u < 2; ++u)
#pragma unroll
                for (int tn = 0; tn < 4; ++tn)
                    acc[h * 2 + u][tn] = __builtin_amdgcn_mfma_f32_16x16x32_bf16(afr[u], bfr[tn], acc[h * 2 + u][tn], 0, 0, 0);
        }

        // item5: gA(kt+1) landed (B(kt+1)+gA(kt+2) stay in flight); cvt+write A(kt+1)
        if (kt < 14) {
            asm volatile("s_waitcnt vmcnt(4)" ::: "memory");
            WRITE_A(kt + 1);
        } else if (kt == 14) {
            asm volatile("s_waitcnt vmcnt(2)" ::: "memory");   // only B(15) in flight
            WRITE_A(15);
        }
    }
#undef LOAD_GA
#undef STAGE_B
#undef WRITE_A

    // ---- epilogue: C/D layout col=lane&15, row=(lane>>4)*4+r ----
    const int col = l & 15;
    const int rq = (l >> 4) * 4;
#pragma unroll
    for (int tm = 0; tm < 4; ++tm) {
#pragma unroll
        for (int r = 0; r < 4; ++r) {
            const int m = m_base + wm * 64 + tm * 16 + rq + r;
            if (m < NN) {
                const float fl = (float)flags[m];
                float* orow = out + (size_t)m * ND + wn * 64 + col;
#pragma unroll
                for (int tn = 0; tn < 4; ++tn)
                    orow[tn * 16] = acc[tm][tn][r] * fl;
            }
        }
    }
}

extern "C" void kernel_launch(void* const* d_in, const int* in_sizes, int n_in,
                              void* d_out, int out_size, void* d_ws, size_t ws_size,
                              hipStream_t stream) {
    const float* x = (const float*)d_in[0];          // (N, 512) f32
    const int* edge_index = (const int*)d_in[1];     // (2, E) i32: row0=src, row1=dst
    const float* W = (const float*)d_in[3];          // (512, 256) f32
    float* out = (float*)d_out;                      // (N, 256) f32

    unsigned char* flags = (unsigned char*)d_ws;                       // NN bytes (16B-aligned)
    __hip_bfloat16* Wt = (__hip_bfloat16*)((char*)d_ws + 65536);       // 256 KB

    prep_kernel<<<45, 256, 0, stream>>>(W, Wt, flags);
    flag_set_kernel<<<(EE / 4 + 255) / 256, 256, 0, stream>>>(edge_index + EE, flags);
    gemm_mask_kernel<<<(NN + 127) / 128, 512, 0, stream>>>(x, Wt, flags, out);
}